// Round 1
// baseline (24771.750 us; speedup 1.0000x reference)
//
#include <hip/hip_runtime.h>
#include <hip/hip_cooperative_groups.h>

namespace cg = cooperative_groups;

#define EPSF 1e-8f

// ---------------------------------------------------------------------------
// Pool: mean over spatial (S2 elements) per (b, ch)
// ---------------------------------------------------------------------------
template <int S2>
__global__ __launch_bounds__(256) void pool_kernel(const float* __restrict__ feat,
                                                   float* __restrict__ pooled, int total)
{
    int idx = blockIdx.x * 256 + threadIdx.x;
    if (idx >= total) return;
    const float4* p4 = (const float4*)(feat + (size_t)idx * S2);
    float s = 0.f;
#pragma unroll
    for (int i = 0; i < S2 / 4; ++i) {
        float4 v = p4[i];
        s += v.x + v.y + v.z + v.w;
    }
    pooled[idx] = s * (1.0f / S2);
}

// ---------------------------------------------------------------------------
// LS: emb = relu(pooled @ w + b), then row-normalize -> nout [4096,128]
// one row per block of 128 threads
// ---------------------------------------------------------------------------
__global__ __launch_bounds__(128) void ls_norm_kernel(const float* __restrict__ pooled,
                                                      const float* __restrict__ w,
                                                      const float* __restrict__ bias,
                                                      float* __restrict__ nout, int K)
{
    __shared__ float pl[512];
    __shared__ float red2[2];
    const int b = blockIdx.x, t = threadIdx.x;
    for (int k = t; k < K; k += 128) pl[k] = pooled[(size_t)b * K + k];
    __syncthreads();
    float acc = bias[t];
    for (int k = 0; k < K; ++k) acc = fmaf(pl[k], w[(size_t)k * 128 + t], acc);
    float v = fmaxf(acc, 0.f);
    float ss = v * v;
    for (int off = 32; off > 0; off >>= 1) ss += __shfl_down(ss, off, 64);
    if ((t & 63) == 0) red2[t >> 6] = ss;
    __syncthreads();
    float inv = 1.0f / fmaxf(sqrtf(red2[0] + red2[1]), 1e-12f);
    nout[(size_t)b * 128 + t] = v * inv;
}

// ---------------------------------------------------------------------------
// Normalize embedds rows (d=512) -> nout
// ---------------------------------------------------------------------------
__global__ __launch_bounds__(256) void norm512_kernel(const float* __restrict__ E,
                                                      float* __restrict__ nout)
{
    __shared__ float red4[4];
    const int b = blockIdx.x, t = threadIdx.x;
    float2 v = *(const float2*)(E + (size_t)b * 512 + t * 2);
    float ss = v.x * v.x + v.y * v.y;
    for (int off = 32; off > 0; off >>= 1) ss += __shfl_down(ss, off, 64);
    if ((t & 63) == 0) red4[t >> 6] = ss;
    __syncthreads();
    float inv = 1.0f / fmaxf(sqrtf(red4[0] + red4[1] + red4[2] + red4[3]), 1e-12f);
    float2 o = make_float2(v.x * inv, v.y * inv);
    *(float2*)(nout + (size_t)b * 512 + t * 2) = o;
}

// ---------------------------------------------------------------------------
// A = clamp(n n^T, 0, 1) with zero diag, written raw; per-block sums -> partials
// (mean-threshold + 1-A transform is applied on the fly in gtg_kernel)
// 128x128 tile, 8x8 micro, K-step 16. Grid = 32x32 = 1024 blocks.
// ---------------------------------------------------------------------------
__global__ __launch_bounds__(256) void a_gemm_kernel(const float* __restrict__ N,
                                                     float* __restrict__ A,
                                                     float* __restrict__ partials, int K)
{
    __shared__ float As[16][136];
    __shared__ float Bs[16][136];
    __shared__ float reds[4];
    const int t = threadIdx.x;
    const int bx = blockIdx.x & 31, by = blockIdx.x >> 5;
    const int r0 = by * 128, c0 = bx * 128;
    const int tx = t & 15, ty = t >> 4;
    const int lrow = t >> 2;
    const int lk = (t & 3) * 4;

    float acc[8][8];
#pragma unroll
    for (int i = 0; i < 8; ++i)
#pragma unroll
        for (int j = 0; j < 8; ++j) acc[i][j] = 0.f;

    for (int k0 = 0; k0 < K; k0 += 16) {
        float4 a0 = *(const float4*)(N + (size_t)(r0 + lrow) * K + k0 + lk);
        float4 a1 = *(const float4*)(N + (size_t)(r0 + lrow + 64) * K + k0 + lk);
        float4 b0 = *(const float4*)(N + (size_t)(c0 + lrow) * K + k0 + lk);
        float4 b1 = *(const float4*)(N + (size_t)(c0 + lrow + 64) * K + k0 + lk);
        __syncthreads();
        As[lk + 0][lrow] = a0.x; As[lk + 1][lrow] = a0.y; As[lk + 2][lrow] = a0.z; As[lk + 3][lrow] = a0.w;
        As[lk + 0][lrow + 64] = a1.x; As[lk + 1][lrow + 64] = a1.y; As[lk + 2][lrow + 64] = a1.z; As[lk + 3][lrow + 64] = a1.w;
        Bs[lk + 0][lrow] = b0.x; Bs[lk + 1][lrow] = b0.y; Bs[lk + 2][lrow] = b0.z; Bs[lk + 3][lrow] = b0.w;
        Bs[lk + 0][lrow + 64] = b1.x; Bs[lk + 1][lrow + 64] = b1.y; Bs[lk + 2][lrow + 64] = b1.z; Bs[lk + 3][lrow + 64] = b1.w;
        __syncthreads();
#pragma unroll
        for (int kk = 0; kk < 16; ++kk) {
            float av[8], bv[8];
            *(float4*)(av) = *(const float4*)(&As[kk][ty * 8]);
            *(float4*)(av + 4) = *(const float4*)(&As[kk][ty * 8 + 4]);
            *(float4*)(bv) = *(const float4*)(&Bs[kk][tx * 8]);
            *(float4*)(bv + 4) = *(const float4*)(&Bs[kk][tx * 8 + 4]);
#pragma unroll
            for (int i = 0; i < 8; ++i)
#pragma unroll
                for (int j = 0; j < 8; ++j) acc[i][j] = fmaf(av[i], bv[j], acc[i][j]);
        }
    }

    float lsum = 0.f;
#pragma unroll
    for (int i = 0; i < 8; ++i) {
        const int row = r0 + ty * 8 + i;
        float outv[8];
#pragma unroll
        for (int j = 0; j < 8; ++j) {
            const int col = c0 + tx * 8 + j;
            float v = acc[i][j];
            v = fminf(fmaxf(v, 0.f), 1.f);
            if (row == col) v = 0.f;
            outv[j] = v;
            lsum += v;
        }
        float* Ar = A + (size_t)row * 4096 + c0 + tx * 8;
        *(float4*)Ar = *(float4*)outv;
        *(float4*)(Ar + 4) = *(float4*)(outv + 4);
    }
    for (int off = 32; off > 0; off >>= 1) lsum += __shfl_down(lsum, off, 64);
    if ((t & 63) == 0) reds[t >> 6] = lsum;
    __syncthreads();
    if (t == 0) partials[blockIdx.x] = reds[0] + reds[1] + reds[2] + reds[3];
}

// ---------------------------------------------------------------------------
// Cooperative GTG: 30 iterations of X += X*(Abar@X)/rowsum, Abar = (a<mean)?1:1-a
// grid 512 blocks x 256 threads (2 blocks/CU). X rows padded to 12 floats.
// mode 0: write Xs[b][c*30+t]; mode 1: accumulate entropy -> yt_out = mean ent
// ---------------------------------------------------------------------------
__global__ __launch_bounds__(256, 2) void gtg_kernel(const float* __restrict__ A,
                                                     const float* __restrict__ partials,
                                                     float* scal, float* X, float* P,
                                                     float* Xs, float* ytacc,
                                                     const int* __restrict__ labels,
                                                     float* yt_out, int mode)
{
    cg::grid_group grid = cg::this_grid();
    const int t = threadIdx.x;
    const int blk = blockIdx.x;
    __shared__ float lds[256];
    __shared__ float red[4];

    // ---- phase 0: mean reduce (block 0) + X init (all blocks)
    if (blk == 0) {
        float s = 0.f;
        for (int i = t; i < 1024; i += 256) s += partials[i];
        for (int off = 32; off > 0; off >>= 1) s += __shfl_down(s, off, 64);
        if ((t & 63) == 0) red[t >> 6] = s;
        __syncthreads();
        if (t == 0) scal[0] = (red[0] + red[1] + red[2] + red[3]) * (1.0f / (4096.0f * 4096.0f));
    }
    if (t < 96) {
        int r8 = t / 12, c = t % 12;
        int row = blk * 8 + r8;
        float v;
        if (c >= 10) v = 0.f;
        else if (row < 2048) v = (c == labels[row]) ? 1.f : 0.f;
        else v = 0.1f;
        X[row * 12 + c] = v;
    }
    if (mode == 1 && t < 8) ytacc[blk * 8 + t] = 0.f;

    grid.sync();
    const float mean = scal[0];

    const int bt = blk & 15, jc = blk >> 4;
    const int bcol = bt * 256 + t;
    const int j0 = jc * 128;

    for (int it = 0; it < 30; ++it) {
        // ---- matvec partial: P[jc][bcol][:] = sum_{j in chunk} Abar[j,bcol]*X[j,:]
        float acc[10];
#pragma unroll
        for (int c = 0; c < 10; ++c) acc[c] = 0.f;
        const float* Ap = A + (size_t)j0 * 4096 + bcol;
        const float* Xp = X + j0 * 12;
#pragma unroll 2
        for (int j = 0; j < 128; ++j) {
            float a = Ap[(size_t)j * 4096];
            float aa = (a < mean) ? 1.0f : (1.0f - a);
            float4 x0 = *(const float4*)(Xp + j * 12);
            float4 x1 = *(const float4*)(Xp + j * 12 + 4);
            float2 x2 = *(const float2*)(Xp + j * 12 + 8);
            acc[0] = fmaf(aa, x0.x, acc[0]);
            acc[1] = fmaf(aa, x0.y, acc[1]);
            acc[2] = fmaf(aa, x0.z, acc[2]);
            acc[3] = fmaf(aa, x0.w, acc[3]);
            acc[4] = fmaf(aa, x1.x, acc[4]);
            acc[5] = fmaf(aa, x1.y, acc[5]);
            acc[6] = fmaf(aa, x1.z, acc[6]);
            acc[7] = fmaf(aa, x1.w, acc[7]);
            acc[8] = fmaf(aa, x2.x, acc[8]);
            acc[9] = fmaf(aa, x2.y, acc[9]);
        }
        {
            float* Pp = P + ((size_t)jc * 4096 + bcol) * 12;
            float4 o0 = make_float4(acc[0], acc[1], acc[2], acc[3]);
            float4 o1 = make_float4(acc[4], acc[5], acc[6], acc[7]);
            float2 o2 = make_float2(acc[8], acc[9]);
            *(float4*)Pp = o0;
            *(float4*)(Pp + 4) = o1;
            *(float2*)(Pp + 8) = o2;
        }

        grid.sync();

        // ---- update: rows blk*8 .. blk*8+7, threads (r8, c) for t<80
        const bool act = t < 80;
        const int r8 = t / 10, c = t - r8 * 10;
        const int row = blk * 8 + (act ? r8 : 0);
        float m = 0.f, x = 0.f;
        if (act) {
            float ysum = 0.f;
            for (int k = 0; k < 32; ++k) ysum += P[((size_t)k * 4096 + row) * 12 + c];
            x = X[row * 12 + c];
            m = x * ysum;
        }
        lds[t] = m;
        __syncthreads();
        float dv = 0.f;
        if (act) {
            float s = 0.f;
#pragma unroll
            for (int q = 0; q < 10; ++q) s += lds[r8 * 10 + q];
            dv = m / (s + EPSF);
            float xn = x + dv;
            X[row * 12 + c] = xn;
            if (mode == 0) Xs[(size_t)row * 300 + c * 30 + it] = xn;
        }
        if (mode == 1) {
            float e = act ? (-dv * logf(dv + EPSF)) : 0.f;
            __syncthreads();
            lds[t] = e;
            __syncthreads();
            if (act && c == 0) {
                float ent = 0.f;
#pragma unroll
                for (int q = 0; q < 10; ++q) ent += lds[r8 * 10 + q];
                ytacc[row] += ent;
            }
        }
        grid.sync();
    }

    if (mode == 1 && t < 8) {
        int row = blk * 8 + t;
        yt_out[row] = ytacc[row] * (1.0f / 30.0f);
    }
}

// ---------------------------------------------------------------------------
// MLP layers 1+2 for one level: H2[:, lvl*75 : lvl*75+75] = relu(relu(Xs@w1+b1)@w2+b2)
// 8 rows per block of 256 threads
// ---------------------------------------------------------------------------
__global__ __launch_bounds__(256) void mlp12_kernel(const float* __restrict__ Xs,
                                                    const float* __restrict__ w1,
                                                    const float* __restrict__ b1,
                                                    const float* __restrict__ w2,
                                                    const float* __restrict__ b2,
                                                    float* __restrict__ H2, int lvl)
{
    __shared__ float xs[8][300];
    __shared__ float h1[8][152];
    const int t = threadIdx.x;
    const size_t r0 = (size_t)blockIdx.x * 8;
    for (int i = t; i < 2400; i += 256) xs[i / 300][i % 300] = Xs[r0 * 300 + i];
    __syncthreads();
    if (t < 150) {
        float acc[8];
#pragma unroll
        for (int r = 0; r < 8; ++r) acc[r] = b1[t];
        for (int k = 0; k < 300; ++k) {
            float wv = w1[(size_t)k * 150 + t];
#pragma unroll
            for (int r = 0; r < 8; ++r) acc[r] = fmaf(xs[r][k], wv, acc[r]);
        }
#pragma unroll
        for (int r = 0; r < 8; ++r) h1[r][t] = fmaxf(acc[r], 0.f);
    }
    __syncthreads();
    if (t < 75) {
        float acc[8];
#pragma unroll
        for (int r = 0; r < 8; ++r) acc[r] = b2[t];
        for (int k = 0; k < 150; ++k) {
            float wv = w2[(size_t)k * 75 + t];
#pragma unroll
            for (int r = 0; r < 8; ++r) acc[r] = fmaf(h1[r][k], wv, acc[r]);
        }
#pragma unroll
        for (int r = 0; r < 8; ++r) H2[(r0 + r) * 300 + lvl * 75 + t] = fmaxf(acc[r], 0.f);
    }
}

// ---------------------------------------------------------------------------
// Final: y_pred = H2 @ w3 + b3; also writes labelled_mask
// ---------------------------------------------------------------------------
__global__ __launch_bounds__(256) void final_kernel(const float* __restrict__ H2,
                                                    const float* __restrict__ w3,
                                                    const float* __restrict__ b3,
                                                    float* __restrict__ out)
{
    __shared__ float w[300];
    const int t = threadIdx.x;
    const int b = blockIdx.x * 256 + t;
    for (int i = t; i < 300; i += 256) w[i] = w3[i];
    __syncthreads();
    float acc = b3[0];
    const float4* row = (const float4*)(H2 + (size_t)b * 300);
    for (int k4 = 0; k4 < 75; ++k4) {
        float4 v = row[k4];
        acc += v.x * w[k4 * 4] + v.y * w[k4 * 4 + 1] + v.z * w[k4 * 4 + 2] + v.w * w[k4 * 4 + 3];
    }
    out[b] = acc;
    out[2 * 4096 + b] = (b < 2048) ? 1.0f : 0.0f;
}

// ---------------------------------------------------------------------------
extern "C" void kernel_launch(void* const* d_in, const int* in_sizes, int n_in,
                              void* d_out, int out_size, void* d_ws, size_t ws_size,
                              hipStream_t stream)
{
    (void)in_sizes; (void)n_in; (void)out_size; (void)ws_size;

    const float* feats[4] = {(const float*)d_in[0], (const float*)d_in[1],
                             (const float*)d_in[2], (const float*)d_in[3]};
    const float* embedds = (const float*)d_in[4];
    const int* labels = (const int*)d_in[6];
    const float* lsw[4] = {(const float*)d_in[7], (const float*)d_in[9],
                           (const float*)d_in[11], (const float*)d_in[13]};
    const float* lsb[4] = {(const float*)d_in[8], (const float*)d_in[10],
                           (const float*)d_in[12], (const float*)d_in[14]};
    const float* w1 = (const float*)d_in[15];
    const float* b1 = (const float*)d_in[16];
    const float* w2 = (const float*)d_in[17];
    const float* b2 = (const float*)d_in[18];
    const float* w3 = (const float*)d_in[19];
    const float* b3 = (const float*)d_in[20];

    char* ws = (char*)d_ws;
    float* A       = (float*)(ws + 0);          //  67108864 B
    float* nbuf    = (float*)(ws + 67108864);   //   8388608 B
    float* pooled  = (float*)(ws + 75497472);   //   8388608 B
    float* X       = (float*)(ws + 83886080);   //    196608 B (4096 x 12)
    float* P       = (float*)(ws + 84082688);   //   6291456 B (32 x 4096 x 12)
    float* Xs      = (float*)(ws + 90374144);   //   4915200 B (4096 x 300)
    float* H2      = (float*)(ws + 95289344);   //   4915200 B (4096 x 300)
    float* ytacc   = (float*)(ws + 100204544);  //     16384 B
    float* partials= (float*)(ws + 100220928);  //      4096 B (1024 floats)
    float* scal    = (float*)(ws + 100225024);  //       256 B

    float* out = (float*)d_out;

    const int Cs[4] = {64, 128, 256, 512};
    const int S2s[4] = {64, 64, 16, 16};

    const float* A_c = A;
    const float* part_c = partials;

    for (int lvl = 0; lvl < 4; ++lvl) {
        const int c = Cs[lvl];
        const int total = 4096 * c;
        if (S2s[lvl] == 64)
            pool_kernel<64><<<total / 256, 256, 0, stream>>>(feats[lvl], pooled, total);
        else
            pool_kernel<16><<<total / 256, 256, 0, stream>>>(feats[lvl], pooled, total);
        ls_norm_kernel<<<4096, 128, 0, stream>>>(pooled, lsw[lvl], lsb[lvl], nbuf, c);
        a_gemm_kernel<<<1024, 256, 0, stream>>>(nbuf, A, partials, 128);

        int mode = 0;
        float* yt = out + 4096;  // unused in mode 0
        void* kargs[] = {(void*)&A_c, (void*)&part_c, (void*)&scal, (void*)&X,
                         (void*)&P, (void*)&Xs, (void*)&ytacc, (void*)&labels,
                         (void*)&yt, (void*)&mode};
        hipLaunchCooperativeKernel((void*)gtg_kernel, dim3(512), dim3(256), kargs, 0, stream);

        mlp12_kernel<<<512, 256, 0, stream>>>(Xs, w1, b1, w2, b2, H2, lvl);
    }

    final_kernel<<<16, 256, 0, stream>>>(H2, w3, b3, out);

    // embedds branch -> y_true
    norm512_kernel<<<4096, 256, 0, stream>>>(embedds, nbuf);
    a_gemm_kernel<<<1024, 256, 0, stream>>>(nbuf, A, partials, 512);
    {
        int mode = 1;
        float* yt = out + 4096;
        void* kargs[] = {(void*)&A_c, (void*)&part_c, (void*)&scal, (void*)&X,
                         (void*)&P, (void*)&Xs, (void*)&ytacc, (void*)&labels,
                         (void*)&yt, (void*)&mode};
        hipLaunchCooperativeKernel((void*)gtg_kernel, dim3(512), dim3(256), kargs, 0, stream);
    }
}

// Round 2
// 7417.540 us; speedup vs baseline: 3.3396x; 3.3396x over previous
//
#include <hip/hip_runtime.h>
#include <hip/hip_fp16.h>
#include <hip/hip_cooperative_groups.h>

namespace cg = cooperative_groups;

// ---------------------------------------------------------------------------
// Pool: mean over spatial (S2 elements) per (b, ch)
// ---------------------------------------------------------------------------
template <int S2>
__global__ __launch_bounds__(256) void pool_kernel(const float* __restrict__ feat,
                                                   float* __restrict__ pooled, int total)
{
    int idx = blockIdx.x * 256 + threadIdx.x;
    if (idx >= total) return;
    const float4* p4 = (const float4*)(feat + (size_t)idx * S2);
    float s = 0.f;
#pragma unroll
    for (int i = 0; i < S2 / 4; ++i) {
        float4 v = p4[i];
        s += v.x + v.y + v.z + v.w;
    }
    pooled[idx] = s * (1.0f / S2);
}

// ---------------------------------------------------------------------------
// LS: emb = relu(pooled @ w + b), then row-normalize -> nout [4096,128]
// ---------------------------------------------------------------------------
__global__ __launch_bounds__(128) void ls_norm_kernel(const float* __restrict__ pooled,
                                                      const float* __restrict__ w,
                                                      const float* __restrict__ bias,
                                                      float* __restrict__ nout, int K)
{
    __shared__ float pl[512];
    __shared__ float red2[2];
    const int b = blockIdx.x, t = threadIdx.x;
    for (int k = t; k < K; k += 128) pl[k] = pooled[(size_t)b * K + k];
    __syncthreads();
    float acc = bias[t];
    for (int k = 0; k < K; ++k) acc = fmaf(pl[k], w[(size_t)k * 128 + t], acc);
    float v = fmaxf(acc, 0.f);
    float ss = v * v;
    for (int off = 32; off > 0; off >>= 1) ss += __shfl_down(ss, off, 64);
    if ((t & 63) == 0) red2[t >> 6] = ss;
    __syncthreads();
    float inv = 1.0f / fmaxf(sqrtf(red2[0] + red2[1]), 1e-12f);
    nout[(size_t)b * 128 + t] = v * inv;
}

// ---------------------------------------------------------------------------
// Normalize embedds rows (d=512) -> nout
// ---------------------------------------------------------------------------
__global__ __launch_bounds__(256) void norm512_kernel(const float* __restrict__ E,
                                                      float* __restrict__ nout)
{
    __shared__ float red4[4];
    const int b = blockIdx.x, t = threadIdx.x;
    float2 v = *(const float2*)(E + (size_t)b * 512 + t * 2);
    float ss = v.x * v.x + v.y * v.y;
    for (int off = 32; off > 0; off >>= 1) ss += __shfl_down(ss, off, 64);
    if ((t & 63) == 0) red4[t >> 6] = ss;
    __syncthreads();
    float inv = 1.0f / fmaxf(sqrtf(red4[0] + red4[1] + red4[2] + red4[3]), 1e-12f);
    float2 o = make_float2(v.x * inv, v.y * inv);
    *(float2*)(nout + (size_t)b * 512 + t * 2) = o;
}

// ---------------------------------------------------------------------------
// A16 = fp16(clamp(n n^T, 0, 1), zero diag); fp32 per-block sums -> partials
// 128x128 tile, 8x8 micro. Grid = 1024 blocks.
// ---------------------------------------------------------------------------
__global__ __launch_bounds__(256) void a_gemm_kernel(const float* __restrict__ N,
                                                     __half* __restrict__ A16,
                                                     float* __restrict__ partials, int K)
{
    __shared__ float As[16][136];
    __shared__ float Bs[16][136];
    __shared__ float reds[4];
    const int t = threadIdx.x;
    const int bx = blockIdx.x & 31, by = blockIdx.x >> 5;
    const int r0 = by * 128, c0 = bx * 128;
    const int tx = t & 15, ty = t >> 4;
    const int lrow = t >> 2;
    const int lk = (t & 3) * 4;

    float acc[8][8];
#pragma unroll
    for (int i = 0; i < 8; ++i)
#pragma unroll
        for (int j = 0; j < 8; ++j) acc[i][j] = 0.f;

    for (int k0 = 0; k0 < K; k0 += 16) {
        float4 a0 = *(const float4*)(N + (size_t)(r0 + lrow) * K + k0 + lk);
        float4 a1 = *(const float4*)(N + (size_t)(r0 + lrow + 64) * K + k0 + lk);
        float4 b0 = *(const float4*)(N + (size_t)(c0 + lrow) * K + k0 + lk);
        float4 b1 = *(const float4*)(N + (size_t)(c0 + lrow + 64) * K + k0 + lk);
        __syncthreads();
        As[lk + 0][lrow] = a0.x; As[lk + 1][lrow] = a0.y; As[lk + 2][lrow] = a0.z; As[lk + 3][lrow] = a0.w;
        As[lk + 0][lrow + 64] = a1.x; As[lk + 1][lrow + 64] = a1.y; As[lk + 2][lrow + 64] = a1.z; As[lk + 3][lrow + 64] = a1.w;
        Bs[lk + 0][lrow] = b0.x; Bs[lk + 1][lrow] = b0.y; Bs[lk + 2][lrow] = b0.z; Bs[lk + 3][lrow] = b0.w;
        Bs[lk + 0][lrow + 64] = b1.x; Bs[lk + 1][lrow + 64] = b1.y; Bs[lk + 2][lrow + 64] = b1.z; Bs[lk + 3][lrow + 64] = b1.w;
        __syncthreads();
#pragma unroll
        for (int kk = 0; kk < 16; ++kk) {
            float av[8], bv[8];
            *(float4*)(av) = *(const float4*)(&As[kk][ty * 8]);
            *(float4*)(av + 4) = *(const float4*)(&As[kk][ty * 8 + 4]);
            *(float4*)(bv) = *(const float4*)(&Bs[kk][tx * 8]);
            *(float4*)(bv + 4) = *(const float4*)(&Bs[kk][tx * 8 + 4]);
#pragma unroll
            for (int i = 0; i < 8; ++i)
#pragma unroll
                for (int j = 0; j < 8; ++j) acc[i][j] = fmaf(av[i], bv[j], acc[i][j]);
        }
    }

    float lsum = 0.f;
#pragma unroll
    for (int i = 0; i < 8; ++i) {
        const int row = r0 + ty * 8 + i;
        __half outh[8];
#pragma unroll
        for (int j = 0; j < 8; ++j) {
            const int col = c0 + tx * 8 + j;
            float v = acc[i][j];
            v = fminf(fmaxf(v, 0.f), 1.f);
            if (row == col) v = 0.f;
            outh[j] = __float2half(v);
            lsum += v;
        }
        *(uint4*)(A16 + (size_t)row * 4096 + c0 + tx * 8) = *(uint4*)outh;
    }
    for (int off = 32; off > 0; off >>= 1) lsum += __shfl_down(lsum, off, 64);
    if ((t & 63) == 0) reds[t >> 6] = lsum;
    __syncthreads();
    if (t == 0) partials[blockIdx.x] = reds[0] + reds[1] + reds[2] + reds[3];
}

// ---------------------------------------------------------------------------
// mean of A from per-block partials
// ---------------------------------------------------------------------------
__global__ __launch_bounds__(256) void mean_kernel(const float* __restrict__ partials,
                                                   float* __restrict__ scal)
{
    __shared__ float red[4];
    const int t = threadIdx.x;
    float s = 0.f;
    for (int i = t; i < 1024; i += 256) s += partials[i];
    for (int off = 32; off > 0; off >>= 1) s += __shfl_down(s, off, 64);
    if ((t & 63) == 0) red[t >> 6] = s;
    __syncthreads();
    if (t == 0) scal[0] = (red[0] + red[1] + red[2] + red[3]) * (1.0f / 16777216.0f);
}

// ---------------------------------------------------------------------------
// Abar = (a < mean) ? 1 : 1-a   (fp16 in, fp16 out), 8 elems/thread
// ---------------------------------------------------------------------------
__global__ __launch_bounds__(256) void abar_kernel(const __half* __restrict__ raw,
                                                   __half* __restrict__ abar,
                                                   const float* __restrict__ scal)
{
    const float mean = scal[0];
    const size_t i = ((size_t)blockIdx.x * 256 + threadIdx.x) * 8;
    uint4 u = *(const uint4*)(raw + i);
    __half hin[8]; *(uint4*)hin = u;
    __half hout[8];
#pragma unroll
    for (int k = 0; k < 8; ++k) {
        float a = __half2float(hin[k]);
        float v = (a < mean) ? 1.0f : (1.0f - a);
        hout[k] = __float2half(v);
    }
    *(uint4*)(abar + i) = *(uint4*)hout;
}

// ---------------------------------------------------------------------------
// Cooperative GTG, row-parallel. 256 blocks x 512 threads, 16 rows/block.
// X master fp32 in LDS per block; fp16 mirror Xf16t[10][4096] in global for
// cross-block exchange; full X staged transposed in LDS each iteration.
// Wave w: row-group rg=w>>1 (4 rows), j-half h=w&1. Lane handles j={2l,2l+1}+q*128.
// ---------------------------------------------------------------------------
__global__ __launch_bounds__(512, 1) void gtg_kernel(const __half* __restrict__ Abar,
                                                     const int* __restrict__ labels,
                                                     __half* __restrict__ Xf16t,
                                                     float* __restrict__ Xs,
                                                     float* __restrict__ yt_out, int mode)
{
    cg::grid_group grid = cg::this_grid();
    __shared__ __half xs[40960];       // [10][4096] transposed X, fp16
    __shared__ float red[8][40];
    __shared__ float mlds[160];
    __shared__ float Xlds[160];        // [16][10] fp32 master for this block's rows
    __shared__ float ytacc[16];

    const int t = threadIdx.x;
    const int blk = blockIdx.x;
    const int lane = t & 63, wave = t >> 6;
    const int rg = wave >> 1, h = wave & 1;
    const int row0 = blk * 16 + rg * 4;

    const int r_ = t / 10, c_ = t - r_ * 10;   // update-phase coords (t<160)
    const int urow = blk * 16 + r_;

    // ---- init X0
    if (t < 160) {
        float v = (urow < 2048) ? ((labels[urow] == c_) ? 1.0f : 0.0f) : 0.1f;
        Xlds[t] = v;
        Xf16t[c_ * 4096 + urow] = __float2half(v);
    }
    if (t < 16) ytacc[t] = 0.f;
    grid.sync();

    const int jbase0 = h * 2048 + 2 * lane;

    for (int it = 0; it < 30; ++it) {
        // ---- stage full X (fp16, transposed) into LDS
        {
            const uint4* src = (const uint4*)Xf16t;
            uint4* dst = (uint4*)xs;
#pragma unroll
            for (int s = 0; s < 10; ++s) dst[t + s * 512] = src[t + s * 512];
        }
        __syncthreads();

        // ---- matvec: acc[r][c] = sum over this wave's j of Abar[row0+r][j]*X[j][c]
        float acc[4][10];
#pragma unroll
        for (int r = 0; r < 4; ++r)
#pragma unroll
            for (int c = 0; c < 10; ++c) acc[r][c] = 0.f;

        const __half* A0 = Abar + (size_t)row0 * 4096 + jbase0;
        const __half* xbase = xs + jbase0;
#pragma unroll 2
        for (int q = 0; q < 16; ++q) {
            const int jb = q * 128;
            __half2 a0 = *(const __half2*)(A0 + jb);
            __half2 a1 = *(const __half2*)(A0 + 4096 + jb);
            __half2 a2 = *(const __half2*)(A0 + 8192 + jb);
            __half2 a3 = *(const __half2*)(A0 + 12288 + jb);
            float a0l = __low2float(a0), a0h = __high2float(a0);
            float a1l = __low2float(a1), a1h = __high2float(a1);
            float a2l = __low2float(a2), a2h = __high2float(a2);
            float a3l = __low2float(a3), a3h = __high2float(a3);
#pragma unroll
            for (int c = 0; c < 10; ++c) {
                __half2 xv = *(const __half2*)(xbase + c * 4096 + jb);
                float xl = __low2float(xv), xh = __high2float(xv);
                acc[0][c] = fmaf(a0l, xl, fmaf(a0h, xh, acc[0][c]));
                acc[1][c] = fmaf(a1l, xl, fmaf(a1h, xh, acc[1][c]));
                acc[2][c] = fmaf(a2l, xl, fmaf(a2h, xh, acc[2][c]));
                acc[3][c] = fmaf(a3l, xl, fmaf(a3h, xh, acc[3][c]));
            }
        }

        // ---- full-wave butterfly reduce, then lane 0 publishes 40 partials
#pragma unroll
        for (int r = 0; r < 4; ++r)
#pragma unroll
            for (int c = 0; c < 10; ++c) {
                float v = acc[r][c];
                v += __shfl_xor(v, 1, 64);
                v += __shfl_xor(v, 2, 64);
                v += __shfl_xor(v, 4, 64);
                v += __shfl_xor(v, 8, 64);
                v += __shfl_xor(v, 16, 64);
                v += __shfl_xor(v, 32, 64);
                acc[r][c] = v;
            }
        if (lane == 0) {
#pragma unroll
            for (int r = 0; r < 4; ++r)
#pragma unroll
                for (int c = 0; c < 10; ++c) red[wave][r * 10 + c] = acc[r][c];
        }
        __syncthreads();

        // ---- row update (block-local)
        float m = 0.f, x = 0.f, div = 0.f;
        if (t < 160) {
            const int rgu = r_ >> 2, rr = r_ & 3;
            float y = red[2 * rgu][rr * 10 + c_] + red[2 * rgu + 1][rr * 10 + c_];
            x = Xlds[t];
            m = x * y;
            mlds[t] = m;
        }
        __syncthreads();
        if (t < 160) {
            float s = 0.f;
            const int base = r_ * 10;
#pragma unroll
            for (int q = 0; q < 10; ++q) s += mlds[base + q];
            div = m / (s + 1e-8f);
            float xn = x + div;
            Xlds[t] = xn;
            Xf16t[c_ * 4096 + urow] = __float2half(xn);
            if (mode == 0) Xs[(size_t)urow * 300 + c_ * 30 + it] = xn;
        }
        if (mode == 1) {
            __syncthreads();
            if (t < 160) mlds[t] = -div * logf(div + 1e-8f);
            __syncthreads();
            if (t < 160 && c_ == 0) {
                float e = 0.f;
#pragma unroll
                for (int q = 0; q < 10; ++q) e += mlds[t + q];
                ytacc[r_] += e;
            }
        }
        grid.sync();
    }

    if (mode == 1 && t < 16) yt_out[blk * 16 + t] = ytacc[t] * (1.0f / 30.0f);
}

// ---------------------------------------------------------------------------
// MLP layers 1+2 for one level
// ---------------------------------------------------------------------------
__global__ __launch_bounds__(256) void mlp12_kernel(const float* __restrict__ Xs,
                                                    const float* __restrict__ w1,
                                                    const float* __restrict__ b1,
                                                    const float* __restrict__ w2,
                                                    const float* __restrict__ b2,
                                                    float* __restrict__ H2, int lvl)
{
    __shared__ float xsh[8][300];
    __shared__ float h1[8][152];
    const int t = threadIdx.x;
    const size_t r0 = (size_t)blockIdx.x * 8;
    for (int i = t; i < 2400; i += 256) xsh[i / 300][i % 300] = Xs[r0 * 300 + i];
    __syncthreads();
    if (t < 150) {
        float acc[8];
#pragma unroll
        for (int r = 0; r < 8; ++r) acc[r] = b1[t];
        for (int k = 0; k < 300; ++k) {
            float wv = w1[(size_t)k * 150 + t];
#pragma unroll
            for (int r = 0; r < 8; ++r) acc[r] = fmaf(xsh[r][k], wv, acc[r]);
        }
#pragma unroll
        for (int r = 0; r < 8; ++r) h1[r][t] = fmaxf(acc[r], 0.f);
    }
    __syncthreads();
    if (t < 75) {
        float acc[8];
#pragma unroll
        for (int r = 0; r < 8; ++r) acc[r] = b2[t];
        for (int k = 0; k < 150; ++k) {
            float wv = w2[(size_t)k * 75 + t];
#pragma unroll
            for (int r = 0; r < 8; ++r) acc[r] = fmaf(h1[r][k], wv, acc[r]);
        }
#pragma unroll
        for (int r = 0; r < 8; ++r) H2[(r0 + r) * 300 + lvl * 75 + t] = fmaxf(acc[r], 0.f);
    }
}

// ---------------------------------------------------------------------------
// Final: y_pred = H2 @ w3 + b3; also writes labelled_mask
// ---------------------------------------------------------------------------
__global__ __launch_bounds__(256) void final_kernel(const float* __restrict__ H2,
                                                    const float* __restrict__ w3,
                                                    const float* __restrict__ b3,
                                                    float* __restrict__ out)
{
    __shared__ float w[300];
    const int t = threadIdx.x;
    const int b = blockIdx.x * 256 + t;
    for (int i = t; i < 300; i += 256) w[i] = w3[i];
    __syncthreads();
    float acc = b3[0];
    const float4* row = (const float4*)(H2 + (size_t)b * 300);
    for (int k4 = 0; k4 < 75; ++k4) {
        float4 v = row[k4];
        acc += v.x * w[k4 * 4] + v.y * w[k4 * 4 + 1] + v.z * w[k4 * 4 + 2] + v.w * w[k4 * 4 + 3];
    }
    out[b] = acc;
    out[2 * 4096 + b] = (b < 2048) ? 1.0f : 0.0f;
}

// ---------------------------------------------------------------------------
extern "C" void kernel_launch(void* const* d_in, const int* in_sizes, int n_in,
                              void* d_out, int out_size, void* d_ws, size_t ws_size,
                              hipStream_t stream)
{
    (void)in_sizes; (void)n_in; (void)out_size; (void)ws_size;

    const float* feats[4] = {(const float*)d_in[0], (const float*)d_in[1],
                             (const float*)d_in[2], (const float*)d_in[3]};
    const float* embedds = (const float*)d_in[4];
    const int* labels = (const int*)d_in[6];
    const float* lsw[4] = {(const float*)d_in[7], (const float*)d_in[9],
                           (const float*)d_in[11], (const float*)d_in[13]};
    const float* lsb[4] = {(const float*)d_in[8], (const float*)d_in[10],
                           (const float*)d_in[12], (const float*)d_in[14]};
    const float* w1 = (const float*)d_in[15];
    const float* b1 = (const float*)d_in[16];
    const float* w2 = (const float*)d_in[17];
    const float* b2 = (const float*)d_in[18];
    const float* w3 = (const float*)d_in[19];
    const float* b3 = (const float*)d_in[20];

    char* ws = (char*)d_ws;
    __half* A16raw  = (__half*)(ws + 0);          // 33554432 B
    __half* Abar16  = (__half*)(ws + 33554432);   // 33554432 B
    float* nbuf     = (float*)(ws + 67108864);    //  8388608 B
    float* pooled   = (float*)(ws + 75497472);    //  8388608 B
    __half* Xf16t   = (__half*)(ws + 83886080);   //   131072 B (pad)
    float* Xs       = (float*)(ws + 84017152);    //  4915200 B
    float* H2       = (float*)(ws + 88932352);    //  4915200 B
    float* partials = (float*)(ws + 93847552);    //     4096 B
    float* scal     = (float*)(ws + 93851648);    //      256 B

    float* out = (float*)d_out;

    const int Cs[4] = {64, 128, 256, 512};
    const int S2s[4] = {64, 64, 16, 16};

    const __half* Abar_c = Abar16;

    for (int lvl = 0; lvl < 4; ++lvl) {
        const int c = Cs[lvl];
        const int total = 4096 * c;
        if (S2s[lvl] == 64)
            pool_kernel<64><<<total / 256, 256, 0, stream>>>(feats[lvl], pooled, total);
        else
            pool_kernel<16><<<total / 256, 256, 0, stream>>>(feats[lvl], pooled, total);
        ls_norm_kernel<<<4096, 128, 0, stream>>>(pooled, lsw[lvl], lsb[lvl], nbuf, c);
        a_gemm_kernel<<<1024, 256, 0, stream>>>(nbuf, A16raw, partials, 128);
        mean_kernel<<<1, 256, 0, stream>>>(partials, scal);
        abar_kernel<<<8192, 256, 0, stream>>>(A16raw, Abar16, scal);

        int mode = 0;
        float* yt = out + 4096;  // unused in mode 0
        void* kargs[] = {(void*)&Abar_c, (void*)&labels, (void*)&Xf16t,
                         (void*)&Xs, (void*)&yt, (void*)&mode};
        hipLaunchCooperativeKernel((void*)gtg_kernel, dim3(256), dim3(512), kargs, 0, stream);

        mlp12_kernel<<<512, 256, 0, stream>>>(Xs, w1, b1, w2, b2, H2, lvl);
    }

    final_kernel<<<16, 256, 0, stream>>>(H2, w3, b3, out);

    // embedds branch -> y_true
    norm512_kernel<<<4096, 256, 0, stream>>>(embedds, nbuf);
    a_gemm_kernel<<<1024, 256, 0, stream>>>(nbuf, A16raw, partials, 512);
    mean_kernel<<<1, 256, 0, stream>>>(partials, scal);
    abar_kernel<<<8192, 256, 0, stream>>>(A16raw, Abar16, scal);
    {
        int mode = 1;
        float* yt = out + 4096;
        void* kargs[] = {(void*)&Abar_c, (void*)&labels, (void*)&Xf16t,
                         (void*)&Xs, (void*)&yt, (void*)&mode};
        hipLaunchCooperativeKernel((void*)gtg_kernel, dim3(256), dim3(512), kargs, 0, stream);
    }
}

// Round 3
// 2529.259 us; speedup vs baseline: 9.7941x; 2.9327x over previous
//
#include <hip/hip_runtime.h>
#include <hip/hip_fp16.h>

typedef __attribute__((ext_vector_type(2))) _Float16 half2r;

// ---------------------------------------------------------------------------
// Pool: mean over spatial (S2 elements) per (b, ch)
// ---------------------------------------------------------------------------
template <int S2>
__global__ __launch_bounds__(256) void pool_kernel(const float* __restrict__ feat,
                                                   float* __restrict__ pooled, int total)
{
    int idx = blockIdx.x * 256 + threadIdx.x;
    if (idx >= total) return;
    const float4* p4 = (const float4*)(feat + (size_t)idx * S2);
    float s = 0.f;
#pragma unroll
    for (int i = 0; i < S2 / 4; ++i) {
        float4 v = p4[i];
        s += v.x + v.y + v.z + v.w;
    }
    pooled[idx] = s * (1.0f / S2);
}

// ---------------------------------------------------------------------------
// LS: emb = relu(pooled @ w + b), then row-normalize -> nout [4096,128]
// ---------------------------------------------------------------------------
__global__ __launch_bounds__(128) void ls_norm_kernel(const float* __restrict__ pooled,
                                                      const float* __restrict__ w,
                                                      const float* __restrict__ bias,
                                                      float* __restrict__ nout, int K)
{
    __shared__ float pl[512];
    __shared__ float red2[2];
    const int b = blockIdx.x, t = threadIdx.x;
    for (int k = t; k < K; k += 128) pl[k] = pooled[(size_t)b * K + k];
    __syncthreads();
    float acc = bias[t];
    for (int k = 0; k < K; ++k) acc = fmaf(pl[k], w[(size_t)k * 128 + t], acc);
    float v = fmaxf(acc, 0.f);
    float ss = v * v;
    for (int off = 32; off > 0; off >>= 1) ss += __shfl_down(ss, off, 64);
    if ((t & 63) == 0) red2[t >> 6] = ss;
    __syncthreads();
    float inv = 1.0f / fmaxf(sqrtf(red2[0] + red2[1]), 1e-12f);
    nout[(size_t)b * 128 + t] = v * inv;
}

// ---------------------------------------------------------------------------
// Normalize embedds rows (d=512) -> nout
// ---------------------------------------------------------------------------
__global__ __launch_bounds__(256) void norm512_kernel(const float* __restrict__ E,
                                                      float* __restrict__ nout)
{
    __shared__ float red4[4];
    const int b = blockIdx.x, t = threadIdx.x;
    float2 v = *(const float2*)(E + (size_t)b * 512 + t * 2);
    float ss = v.x * v.x + v.y * v.y;
    for (int off = 32; off > 0; off >>= 1) ss += __shfl_down(ss, off, 64);
    if ((t & 63) == 0) red4[t >> 6] = ss;
    __syncthreads();
    float inv = 1.0f / fmaxf(sqrtf(red4[0] + red4[1] + red4[2] + red4[3]), 1e-12f);
    float2 o = make_float2(v.x * inv, v.y * inv);
    *(float2*)(nout + (size_t)b * 512 + t * 2) = o;
}

// ---------------------------------------------------------------------------
// A16 = fp16(clamp(n n^T, 0, 1), zero diag); fp32 per-block sums -> partials
// ---------------------------------------------------------------------------
__global__ __launch_bounds__(256) void a_gemm_kernel(const float* __restrict__ N,
                                                     __half* __restrict__ A16,
                                                     float* __restrict__ partials, int K)
{
    __shared__ float As[16][136];
    __shared__ float Bs[16][136];
    __shared__ float reds[4];
    const int t = threadIdx.x;
    const int bx = blockIdx.x & 31, by = blockIdx.x >> 5;
    const int r0 = by * 128, c0 = bx * 128;
    const int tx = t & 15, ty = t >> 4;
    const int lrow = t >> 2;
    const int lk = (t & 3) * 4;

    float acc[8][8];
#pragma unroll
    for (int i = 0; i < 8; ++i)
#pragma unroll
        for (int j = 0; j < 8; ++j) acc[i][j] = 0.f;

    for (int k0 = 0; k0 < K; k0 += 16) {
        float4 a0 = *(const float4*)(N + (size_t)(r0 + lrow) * K + k0 + lk);
        float4 a1 = *(const float4*)(N + (size_t)(r0 + lrow + 64) * K + k0 + lk);
        float4 b0 = *(const float4*)(N + (size_t)(c0 + lrow) * K + k0 + lk);
        float4 b1 = *(const float4*)(N + (size_t)(c0 + lrow + 64) * K + k0 + lk);
        __syncthreads();
        As[lk + 0][lrow] = a0.x; As[lk + 1][lrow] = a0.y; As[lk + 2][lrow] = a0.z; As[lk + 3][lrow] = a0.w;
        As[lk + 0][lrow + 64] = a1.x; As[lk + 1][lrow + 64] = a1.y; As[lk + 2][lrow + 64] = a1.z; As[lk + 3][lrow + 64] = a1.w;
        Bs[lk + 0][lrow] = b0.x; Bs[lk + 1][lrow] = b0.y; Bs[lk + 2][lrow] = b0.z; Bs[lk + 3][lrow] = b0.w;
        Bs[lk + 0][lrow + 64] = b1.x; Bs[lk + 1][lrow + 64] = b1.y; Bs[lk + 2][lrow + 64] = b1.z; Bs[lk + 3][lrow + 64] = b1.w;
        __syncthreads();
#pragma unroll
        for (int kk = 0; kk < 16; ++kk) {
            float av[8], bv[8];
            *(float4*)(av) = *(const float4*)(&As[kk][ty * 8]);
            *(float4*)(av + 4) = *(const float4*)(&As[kk][ty * 8 + 4]);
            *(float4*)(bv) = *(const float4*)(&Bs[kk][tx * 8]);
            *(float4*)(bv + 4) = *(const float4*)(&Bs[kk][tx * 8 + 4]);
#pragma unroll
            for (int i = 0; i < 8; ++i)
#pragma unroll
                for (int j = 0; j < 8; ++j) acc[i][j] = fmaf(av[i], bv[j], acc[i][j]);
        }
    }

    float lsum = 0.f;
#pragma unroll
    for (int i = 0; i < 8; ++i) {
        const int row = r0 + ty * 8 + i;
        __half outh[8];
#pragma unroll
        for (int j = 0; j < 8; ++j) {
            const int col = c0 + tx * 8 + j;
            float v = acc[i][j];
            v = fminf(fmaxf(v, 0.f), 1.f);
            if (row == col) v = 0.f;
            outh[j] = __float2half(v);
            lsum += v;
        }
        *(uint4*)(A16 + (size_t)row * 4096 + c0 + tx * 8) = *(uint4*)outh;
    }
    for (int off = 32; off > 0; off >>= 1) lsum += __shfl_down(lsum, off, 64);
    if ((t & 63) == 0) reds[t >> 6] = lsum;
    __syncthreads();
    if (t == 0) partials[blockIdx.x] = reds[0] + reds[1] + reds[2] + reds[3];
}

// ---------------------------------------------------------------------------
// mean of A from per-block partials
// ---------------------------------------------------------------------------
__global__ __launch_bounds__(256) void mean_kernel(const float* __restrict__ partials,
                                                   float* __restrict__ scal)
{
    __shared__ float red[4];
    const int t = threadIdx.x;
    float s = 0.f;
    for (int i = t; i < 1024; i += 256) s += partials[i];
    for (int off = 32; off > 0; off >>= 1) s += __shfl_down(s, off, 64);
    if ((t & 63) == 0) red[t >> 6] = s;
    __syncthreads();
    if (t == 0) scal[0] = (red[0] + red[1] + red[2] + red[3]) * (1.0f / 16777216.0f);
}

// ---------------------------------------------------------------------------
// Abar = (a < mean) ? 1 : 1-a  (fp16, in-place safe: pure elementwise)
// ---------------------------------------------------------------------------
__global__ __launch_bounds__(256) void abar_kernel(const __half* raw, __half* abar,
                                                   const float* scal)
{
    const float mean = scal[0];
    const size_t i = ((size_t)blockIdx.x * 256 + threadIdx.x) * 8;
    uint4 u = *(const uint4*)(raw + i);
    __half hin[8]; *(uint4*)hin = u;
    __half hout[8];
#pragma unroll
    for (int k = 0; k < 8; ++k) {
        float a = __half2float(hin[k]);
        float v = (a < mean) ? 1.0f : (1.0f - a);
        hout[k] = __float2half(v);
    }
    *(uint4*)(abar + i) = *(uint4*)hout;
}

// ---------------------------------------------------------------------------
// X0 init: Xf32[p][row][c], Xf16[p][c][row] for all 5 problems
// ---------------------------------------------------------------------------
__global__ __launch_bounds__(256) void init_kernel(const int* __restrict__ labels,
                                                   __half* __restrict__ Xf16,
                                                   float* __restrict__ Xf32)
{
    const int idx = blockIdx.x * 256 + threadIdx.x;   // 5*4096*10 = 204800
    const int p = idx / 40960;
    const int rem = idx - p * 40960;
    const int row = rem / 10, c = rem - row * 10;
    float v = (row < 2048) ? ((labels[row] == c) ? 1.0f : 0.0f) : 0.1f;
    Xf32[(size_t)p * 40960 + row * 10 + c] = v;
    Xf16[(size_t)p * 40960 + c * 4096 + row] = __float2half(v);
}

// ---------------------------------------------------------------------------
// One GTG iteration. Block: 256 threads, 16 rows of one problem.
// p = pbase + blk>>8. Reads X16i/X32i, writes X16o/X32o (double buffer).
// p<4: store Xs trajectory; p==4: accumulate entropy into ytacc.
// ---------------------------------------------------------------------------
__global__ __launch_bounds__(256, 2) void gtg_iter_kernel(
    const __half* __restrict__ Abar,
    const __half* __restrict__ X16i, __half* __restrict__ X16o,
    const float* __restrict__ X32i, float* __restrict__ X32o,
    float* __restrict__ Xs, float* __restrict__ ytacc,
    int it, int pbase)
{
    __shared__ __half xs[40960];   // [10][4096]
    const int t = threadIdx.x;
    const int blk = blockIdx.x;
    const int p = pbase + (blk >> 8);
    const int pl = p - pbase;
    const int lane = t & 63, wave = t >> 6;
    const int row0 = (blk & 255) * 16 + wave * 4;

    // stage this problem's X (80 KB) into LDS
    {
        const uint4* src = (const uint4*)(X16i + (size_t)p * 40960);
        uint4* dst = (uint4*)xs;
#pragma unroll
        for (int s = 0; s < 20; ++s) dst[t + s * 256] = src[t + s * 256];
    }
    __syncthreads();

    float acc[4][10];
#pragma unroll
    for (int r = 0; r < 4; ++r)
#pragma unroll
        for (int c = 0; c < 10; ++c) acc[r][c] = 0.f;

    const __half* Arow = Abar + (size_t)pl * 16777216 + (size_t)row0 * 4096;

#pragma unroll 2
    for (int step = 0; step < 16; ++step) {
        const int j = step * 256 + lane * 4;
        uint2 a0 = *(const uint2*)&Arow[j];
        uint2 a1 = *(const uint2*)&Arow[4096 + j];
        uint2 a2 = *(const uint2*)&Arow[8192 + j];
        uint2 a3 = *(const uint2*)&Arow[12288 + j];
        half2r a0l = __builtin_bit_cast(half2r, a0.x), a0h = __builtin_bit_cast(half2r, a0.y);
        half2r a1l = __builtin_bit_cast(half2r, a1.x), a1h = __builtin_bit_cast(half2r, a1.y);
        half2r a2l = __builtin_bit_cast(half2r, a2.x), a2h = __builtin_bit_cast(half2r, a2.y);
        half2r a3l = __builtin_bit_cast(half2r, a3.x), a3h = __builtin_bit_cast(half2r, a3.y);
#pragma unroll
        for (int c = 0; c < 10; ++c) {
            uint2 xv = *(const uint2*)&xs[c * 4096 + j];
            half2r xl = __builtin_bit_cast(half2r, xv.x);
            half2r xh = __builtin_bit_cast(half2r, xv.y);
            acc[0][c] = __builtin_amdgcn_fdot2(a0l, xl, acc[0][c], false);
            acc[0][c] = __builtin_amdgcn_fdot2(a0h, xh, acc[0][c], false);
            acc[1][c] = __builtin_amdgcn_fdot2(a1l, xl, acc[1][c], false);
            acc[1][c] = __builtin_amdgcn_fdot2(a1h, xh, acc[1][c], false);
            acc[2][c] = __builtin_amdgcn_fdot2(a2l, xl, acc[2][c], false);
            acc[2][c] = __builtin_amdgcn_fdot2(a2h, xh, acc[2][c], false);
            acc[3][c] = __builtin_amdgcn_fdot2(a3l, xl, acc[3][c], false);
            acc[3][c] = __builtin_amdgcn_fdot2(a3h, xh, acc[3][c], false);
        }
    }

    // full-wave butterfly: every lane ends with the complete Y values
#pragma unroll
    for (int r = 0; r < 4; ++r)
#pragma unroll
        for (int c = 0; c < 10; ++c) {
            float v = acc[r][c];
            v += __shfl_xor(v, 1, 64);
            v += __shfl_xor(v, 2, 64);
            v += __shfl_xor(v, 4, 64);
            v += __shfl_xor(v, 8, 64);
            v += __shfl_xor(v, 16, 64);
            v += __shfl_xor(v, 32, 64);
            acc[r][c] = v;
        }

    // epilogue: lanes 0,16,32,48 each update one row
    if ((lane & 15) == 0) {
        const int r = lane >> 4;
        const int row = row0 + r;
        const float* xp = X32i + ((size_t)p * 4096 + row) * 10;
        float* xo = X32o + ((size_t)p * 4096 + row) * 10;
        __half* xf = X16o + (size_t)p * 40960 + row;
        float x[10], m[10], s = 0.f;
#pragma unroll
        for (int c = 0; c < 10; ++c) {
            x[c] = xp[c];
            m[c] = x[c] * acc[r][c];
            s += m[c];
        }
        const float inv = 1.0f / (s + 1e-8f);
        if (p < 4) {
            float* xsrow = Xs + ((size_t)p * 4096 + row) * 300 + it;
#pragma unroll
            for (int c = 0; c < 10; ++c) {
                float xn = x[c] + m[c] * inv;
                xo[c] = xn;
                xf[c * 4096] = __float2half(xn);
                xsrow[c * 30] = xn;
            }
        } else {
            float ent = 0.f;
#pragma unroll
            for (int c = 0; c < 10; ++c) {
                float dv = m[c] * inv;
                float xn = x[c] + dv;
                xo[c] = xn;
                xf[c * 4096] = __float2half(xn);
                ent += -dv * logf(dv + 1e-8f);
            }
            float prev = (it == 0) ? 0.f : ytacc[row];
            ytacc[row] = prev + ent;
        }
    }
}

// ---------------------------------------------------------------------------
// MLP layers 1+2 for one level
// ---------------------------------------------------------------------------
__global__ __launch_bounds__(256) void mlp12_kernel(const float* __restrict__ Xs,
                                                    const float* __restrict__ w1,
                                                    const float* __restrict__ b1,
                                                    const float* __restrict__ w2,
                                                    const float* __restrict__ b2,
                                                    float* __restrict__ H2, int lvl)
{
    __shared__ float xsh[8][300];
    __shared__ float h1[8][152];
    const int t = threadIdx.x;
    const size_t r0 = (size_t)blockIdx.x * 8;
    for (int i = t; i < 2400; i += 256) xsh[i / 300][i % 300] = Xs[r0 * 300 + i];
    __syncthreads();
    if (t < 150) {
        float acc[8];
#pragma unroll
        for (int r = 0; r < 8; ++r) acc[r] = b1[t];
        for (int k = 0; k < 300; ++k) {
            float wv = w1[(size_t)k * 150 + t];
#pragma unroll
            for (int r = 0; r < 8; ++r) acc[r] = fmaf(xsh[r][k], wv, acc[r]);
        }
#pragma unroll
        for (int r = 0; r < 8; ++r) h1[r][t] = fmaxf(acc[r], 0.f);
    }
    __syncthreads();
    if (t < 75) {
        float acc[8];
#pragma unroll
        for (int r = 0; r < 8; ++r) acc[r] = b2[t];
        for (int k = 0; k < 150; ++k) {
            float wv = w2[(size_t)k * 75 + t];
#pragma unroll
            for (int r = 0; r < 8; ++r) acc[r] = fmaf(h1[r][k], wv, acc[r]);
        }
#pragma unroll
        for (int r = 0; r < 8; ++r) H2[(r0 + r) * 300 + lvl * 75 + t] = fmaxf(acc[r], 0.f);
    }
}

// ---------------------------------------------------------------------------
// Final: y_pred = H2 @ w3 + b3; y_true = ytacc/30; labelled_mask
// ---------------------------------------------------------------------------
__global__ __launch_bounds__(256) void final_kernel(const float* __restrict__ H2,
                                                    const float* __restrict__ w3,
                                                    const float* __restrict__ b3,
                                                    const float* __restrict__ ytacc,
                                                    float* __restrict__ out)
{
    __shared__ float w[300];
    const int t = threadIdx.x;
    const int b = blockIdx.x * 256 + t;
    for (int i = t; i < 300; i += 256) w[i] = w3[i];
    __syncthreads();
    float acc = b3[0];
    const float4* row = (const float4*)(H2 + (size_t)b * 300);
    for (int k4 = 0; k4 < 75; ++k4) {
        float4 v = row[k4];
        acc += v.x * w[k4 * 4] + v.y * w[k4 * 4 + 1] + v.z * w[k4 * 4 + 2] + v.w * w[k4 * 4 + 3];
    }
    out[b] = acc;
    out[4096 + b] = ytacc[b] * (1.0f / 30.0f);
    out[2 * 4096 + b] = (b < 2048) ? 1.0f : 0.0f;
}

// ---------------------------------------------------------------------------
extern "C" void kernel_launch(void* const* d_in, const int* in_sizes, int n_in,
                              void* d_out, int out_size, void* d_ws, size_t ws_size,
                              hipStream_t stream)
{
    (void)in_sizes; (void)n_in; (void)out_size;

    const float* feats[4] = {(const float*)d_in[0], (const float*)d_in[1],
                             (const float*)d_in[2], (const float*)d_in[3]};
    const float* embedds = (const float*)d_in[4];
    const int* labels = (const int*)d_in[6];
    const float* lsw[4] = {(const float*)d_in[7], (const float*)d_in[9],
                           (const float*)d_in[11], (const float*)d_in[13]};
    const float* lsb[4] = {(const float*)d_in[8], (const float*)d_in[10],
                           (const float*)d_in[12], (const float*)d_in[14]};
    const float* w1 = (const float*)d_in[15];
    const float* b1 = (const float*)d_in[16];
    const float* w2 = (const float*)d_in[17];
    const float* b2 = (const float*)d_in[18];
    const float* w3 = (const float*)d_in[19];
    const float* b3 = (const float*)d_in[20];

    // fused path: 5 Abar matrices resident (5*32MB); else 1 reused
    const bool fused = ws_size >= 211603968ULL;
    const size_t AB_BYTES = fused ? 167772160ULL : 33554432ULL;

    char* ws = (char*)d_ws;
    __half* AbarB   = (__half*)(ws);
    char* base      = ws + AB_BYTES;
    float* pooled   = (float*)(base);                 //  8388608
    float* nbuf     = (float*)(base + 8388608);       //  8388608
    __half* X16     = (__half*)(base + 16777216);     //  2 x 409600
    float* X32      = (float*)(base + 17596416);      //  2 x 819200
    float* Xs       = (float*)(base + 19234816);      //  19660800 (4 problems)
    float* H2       = (float*)(base + 38895616);      //  4915200
    float* ytacc    = (float*)(base + 43810816);      //  16384
    float* partials = (float*)(base + 43827200);      //  4096
    float* scal     = (float*)(base + 43831296);      //  256

    __half* X16b[2] = {X16, X16 + 204800};
    float* X32b[2]  = {X32, X32 + 204800};
    float* out = (float*)d_out;

    const int Cs[4] = {64, 128, 256, 512};
    const int S2s[4] = {64, 64, 16, 16};

    auto run_iters = [&](const __half* Ab, int pbase, int nblocks) {
        init_kernel<<<800, 256, 0, stream>>>(labels, X16b[0], X32b[0]);
        for (int it = 0; it < 30; ++it) {
            const int i = it & 1, o = i ^ 1;
            gtg_iter_kernel<<<nblocks, 256, 0, stream>>>(
                Ab, X16b[i], X16b[o], X32b[i], X32b[o], Xs, ytacc, it, pbase);
        }
    };

    for (int lvl = 0; lvl < 4; ++lvl) {
        const int c = Cs[lvl];
        const int total = 4096 * c;
        if (S2s[lvl] == 64)
            pool_kernel<64><<<total / 256, 256, 0, stream>>>(feats[lvl], pooled, total);
        else
            pool_kernel<16><<<total / 256, 256, 0, stream>>>(feats[lvl], pooled, total);
        ls_norm_kernel<<<4096, 128, 0, stream>>>(pooled, lsw[lvl], lsb[lvl], nbuf, c);
        __half* Ab = AbarB + (fused ? (size_t)lvl * 16777216 : 0);
        a_gemm_kernel<<<1024, 256, 0, stream>>>(nbuf, Ab, partials, 128);
        mean_kernel<<<1, 256, 0, stream>>>(partials, scal);
        abar_kernel<<<8192, 256, 0, stream>>>(Ab, Ab, scal);
        if (!fused) {
            run_iters(Ab, lvl, 256);
            mlp12_kernel<<<512, 256, 0, stream>>>(Xs + (size_t)lvl * 1228800,
                                                  w1, b1, w2, b2, H2, lvl);
        }
    }

    // embeddings branch
    norm512_kernel<<<4096, 256, 0, stream>>>(embedds, nbuf);
    {
        __half* Ab = AbarB + (fused ? (size_t)4 * 16777216 : 0);
        a_gemm_kernel<<<1024, 256, 0, stream>>>(nbuf, Ab, partials, 512);
        mean_kernel<<<1, 256, 0, stream>>>(partials, scal);
        abar_kernel<<<8192, 256, 0, stream>>>(Ab, Ab, scal);
        if (!fused) run_iters(Ab, 4, 256);
    }

    if (fused) {
        run_iters(AbarB, 0, 1280);
        for (int lvl = 0; lvl < 4; ++lvl)
            mlp12_kernel<<<512, 256, 0, stream>>>(Xs + (size_t)lvl * 1228800,
                                                  w1, b1, w2, b2, H2, lvl);
    }

    final_kernel<<<16, 256, 0, stream>>>(H2, w3, b3, ytacc, out);
}

// Round 4
// 1768.190 us; speedup vs baseline: 14.0097x; 1.4304x over previous
//
#include <hip/hip_runtime.h>
#include <hip/hip_fp16.h>

typedef _Float16 f16x8 __attribute__((ext_vector_type(8)));
typedef float f32x4 __attribute__((ext_vector_type(4)));

// ---------------------------------------------------------------------------
// Pool: mean over spatial (S2 elements) per (b, ch)
// ---------------------------------------------------------------------------
template <int S2>
__global__ __launch_bounds__(256) void pool_kernel(const float* __restrict__ feat,
                                                   float* __restrict__ pooled, int total)
{
    int idx = blockIdx.x * 256 + threadIdx.x;
    if (idx >= total) return;
    const float4* p4 = (const float4*)(feat + (size_t)idx * S2);
    float s = 0.f;
#pragma unroll
    for (int i = 0; i < S2 / 4; ++i) {
        float4 v = p4[i];
        s += v.x + v.y + v.z + v.w;
    }
    pooled[idx] = s * (1.0f / S2);
}

// ---------------------------------------------------------------------------
// LS: emb = relu(pooled @ w + b), row-normalize -> fp16 N16 [4096,128]
// ---------------------------------------------------------------------------
__global__ __launch_bounds__(128) void ls_norm_kernel(const float* __restrict__ pooled,
                                                      const float* __restrict__ w,
                                                      const float* __restrict__ bias,
                                                      __half* __restrict__ n16, int K)
{
    __shared__ float pl[512];
    __shared__ float red2[2];
    const int b = blockIdx.x, t = threadIdx.x;
    for (int k = t; k < K; k += 128) pl[k] = pooled[(size_t)b * K + k];
    __syncthreads();
    float acc = bias[t];
    for (int k = 0; k < K; ++k) acc = fmaf(pl[k], w[(size_t)k * 128 + t], acc);
    float v = fmaxf(acc, 0.f);
    float ss = v * v;
    for (int off = 32; off > 0; off >>= 1) ss += __shfl_down(ss, off, 64);
    if ((t & 63) == 0) red2[t >> 6] = ss;
    __syncthreads();
    float inv = 1.0f / fmaxf(sqrtf(red2[0] + red2[1]), 1e-12f);
    n16[(size_t)b * 128 + t] = __float2half(v * inv);
}

// ---------------------------------------------------------------------------
// Normalize embedds rows (d=512) -> fp16 N16 [4096,512]
// ---------------------------------------------------------------------------
__global__ __launch_bounds__(256) void norm512_kernel(const float* __restrict__ E,
                                                      __half* __restrict__ n16)
{
    __shared__ float red4[4];
    const int b = blockIdx.x, t = threadIdx.x;
    float2 v = *(const float2*)(E + (size_t)b * 512 + t * 2);
    float ss = v.x * v.x + v.y * v.y;
    for (int off = 32; off > 0; off >>= 1) ss += __shfl_down(ss, off, 64);
    if ((t & 63) == 0) red4[t >> 6] = ss;
    __syncthreads();
    float inv = 1.0f / fmaxf(sqrtf(red4[0] + red4[1] + red4[2] + red4[3]), 1e-12f);
    __half2 o;
    o.x = __float2half(v.x * inv);
    o.y = __float2half(v.y * inv);
    *(__half2*)(n16 + (size_t)b * 512 + t * 2) = o;
}

// ---------------------------------------------------------------------------
// MFMA GEMM: A16 = fp16(clamp(N16 N16^T, 0, 1), diag=0); block partial sums.
// 128x128 tile, 4 waves 2x2, each wave 64x64 = 4x4 frags of 16x16x32_f16.
// Fragments loaded directly from global (N16 is L2-resident).
// ---------------------------------------------------------------------------
__global__ __launch_bounds__(256) void a_gemm_mfma(const __half* __restrict__ N16,
                                                   __half* __restrict__ A16,
                                                   float* __restrict__ partials, int K)
{
    __shared__ float reds[4];
    const int t = threadIdx.x;
    const int lane = t & 63, wave = t >> 6;
    const int bx = blockIdx.x & 31, by = blockIdx.x >> 5;
    const int wr = wave >> 1, wc = wave & 1;
    const int r0 = by * 128 + wr * 64;
    const int c0 = bx * 128 + wc * 64;
    const int fr = lane & 15;
    const int fk = (lane >> 4) * 8;

    f32x4 acc[4][4];
#pragma unroll
    for (int i = 0; i < 4; ++i)
#pragma unroll
        for (int j = 0; j < 4; ++j) acc[i][j] = (f32x4){0.f, 0.f, 0.f, 0.f};

    const int nsteps = K >> 5;
    for (int s = 0; s < nsteps; ++s) {
        const int k = s * 32 + fk;
        f16x8 af[4], bf[4];
#pragma unroll
        for (int i = 0; i < 4; ++i) {
            af[i] = *(const f16x8*)(N16 + (size_t)(r0 + i * 16 + fr) * K + k);
            bf[i] = *(const f16x8*)(N16 + (size_t)(c0 + i * 16 + fr) * K + k);
        }
#pragma unroll
        for (int i = 0; i < 4; ++i)
#pragma unroll
            for (int j = 0; j < 4; ++j)
                acc[i][j] = __builtin_amdgcn_mfma_f32_16x16x32_f16(af[i], bf[j], acc[i][j], 0, 0, 0);
    }

    // epilogue: clamp, zero diag, fp16 store, sum
    float lsum = 0.f;
    const int r4 = (lane >> 4) * 4;
#pragma unroll
    for (int i = 0; i < 4; ++i) {
#pragma unroll
        for (int q = 0; q < 4; ++q) {
            const int row = r0 + i * 16 + r4 + q;
#pragma unroll
            for (int j = 0; j < 4; ++j) {
                const int col = c0 + j * 16 + fr;
                float v = acc[i][j][q];
                v = fminf(fmaxf(v, 0.f), 1.f);
                if (row == col) v = 0.f;
                lsum += v;
                A16[(size_t)row * 4096 + col] = __float2half(v);
            }
        }
    }
    for (int off = 32; off > 0; off >>= 1) lsum += __shfl_down(lsum, off, 64);
    if (lane == 0) reds[wave] = lsum;
    __syncthreads();
    if (t == 0) partials[blockIdx.x] = reds[0] + reds[1] + reds[2] + reds[3];
}

// ---------------------------------------------------------------------------
// mean of A from per-block partials
// ---------------------------------------------------------------------------
__global__ __launch_bounds__(256) void mean_kernel(const float* __restrict__ partials,
                                                   float* __restrict__ scal)
{
    __shared__ float red[4];
    const int t = threadIdx.x;
    float s = 0.f;
    for (int i = t; i < 1024; i += 256) s += partials[i];
    for (int off = 32; off > 0; off >>= 1) s += __shfl_down(s, off, 64);
    if ((t & 63) == 0) red[t >> 6] = s;
    __syncthreads();
    if (t == 0) scal[0] = (red[0] + red[1] + red[2] + red[3]) * (1.0f / 16777216.0f);
}

// ---------------------------------------------------------------------------
// Abar = (a < mean) ? 1 : 1-a  (fp16, in-place safe elementwise)
// ---------------------------------------------------------------------------
__global__ __launch_bounds__(256) void abar_kernel(const __half* raw, __half* abar,
                                                   const float* scal)
{
    const float mean = scal[0];
    const size_t i = ((size_t)blockIdx.x * 256 + threadIdx.x) * 8;
    uint4 u = *(const uint4*)(raw + i);
    __half hin[8]; *(uint4*)hin = u;
    __half hout[8];
#pragma unroll
    for (int k = 0; k < 8; ++k) {
        float a = __half2float(hin[k]);
        float v = (a < mean) ? 1.0f : (1.0f - a);
        hout[k] = __float2half(v);
    }
    *(uint4*)(abar + i) = *(uint4*)hout;
}

// ---------------------------------------------------------------------------
// X0 init: Xt (fp16, [p][16][4096], classes padded 10->16) buf0 + pad of buf1;
// X32 (fp32, [p][4096][10]) buf0.
// ---------------------------------------------------------------------------
__global__ __launch_bounds__(256) void init_kernel(const int* __restrict__ labels,
                                                   __half* __restrict__ Xt0,
                                                   __half* __restrict__ Xt1,
                                                   float* __restrict__ X32)
{
    const int idx = blockIdx.x * 256 + threadIdx.x;   // 5*16*4096 = 327680
    const int p = idx >> 16;
    const int rem = idx & 65535;
    const int c = rem >> 12, row = rem & 4095;
    float v;
    if (c >= 10) v = 0.f;
    else if (row < 2048) v = (labels[row] == c) ? 1.0f : 0.0f;
    else v = 0.1f;
    Xt0[idx] = __float2half(v);
    if (c >= 10) Xt1[idx] = __float2half(0.f);
    if (c < 10) X32[((size_t)p * 4096 + row) * 10 + c] = v;
}

// ---------------------------------------------------------------------------
// One GTG iteration via MFMA. Block: 256 threads (4 waves), 16 rows of one
// problem; wave w covers k-quarter [w*1024, w*1024+1024). Y = Abar @ X via
// 16x16x32_f16 MFMA (X transposed fp16, padded to 16 classes), 4KB LDS
// cross-wave reduce, then replicator update. p<4: Xs trajectory; p==4: entropy.
// ---------------------------------------------------------------------------
__global__ __launch_bounds__(256) void gtg_mfma_kernel(
    const __half* __restrict__ Abar,
    const __half* __restrict__ Xt_i, __half* __restrict__ Xt_o,
    const float* __restrict__ X32i, float* __restrict__ X32o,
    float* __restrict__ Xs, float* __restrict__ ytacc, int it, int pbase)
{
    __shared__ float yred[4][256];
    const int t = threadIdx.x;
    const int lane = t & 63, wave = t >> 6;
    const int p = pbase + (blockIdx.x >> 8);
    const int pl = p - pbase;
    const int row0 = (blockIdx.x & 255) * 16;
    const int fr = lane & 15;
    const int fk = (lane >> 4) * 8;

    const __half* Ab = Abar + (size_t)pl * 16777216 + (size_t)(row0 + fr) * 4096;
    const __half* Xb = Xt_i + (size_t)p * 65536 + (size_t)fr * 4096;

    f32x4 acc = {0.f, 0.f, 0.f, 0.f};
    const int k0 = wave * 1024 + fk;
#pragma unroll 4
    for (int s = 0; s < 32; ++s) {
        const int k = k0 + s * 32;
        f16x8 a = *(const f16x8*)(Ab + k);
        f16x8 b = *(const f16x8*)(Xb + k);
        acc = __builtin_amdgcn_mfma_f32_16x16x32_f16(a, b, acc, 0, 0, 0);
    }
    {
        const int r4 = (lane >> 4) * 4;
#pragma unroll
        for (int q = 0; q < 4; ++q)
            yred[wave][(r4 + q) * 16 + fr] = acc[q];
    }
    __syncthreads();

    // update phase: thread t -> row r=t>>4, class c=t&15
    const int r = t >> 4, c = t & 15;
    const int row = row0 + r;
    const float y = yred[0][t] + yred[1][t] + yred[2][t] + yred[3][t];
    const float x = (c < 10) ? X32i[((size_t)p * 4096 + row) * 10 + c] : 0.f;
    const float m = x * y;
    float s = m;
    s += __shfl_xor(s, 1, 16);
    s += __shfl_xor(s, 2, 16);
    s += __shfl_xor(s, 4, 16);
    s += __shfl_xor(s, 8, 16);
    const float dv = m / (s + 1e-8f);
    const float xn = x + dv;
    if (c < 10) {
        X32o[((size_t)p * 4096 + row) * 10 + c] = xn;
        Xt_o[(size_t)p * 65536 + c * 4096 + row] = __float2half(xn);
        if (p < 4) Xs[((size_t)p * 4096 + row) * 300 + c * 30 + it] = xn;
    }
    if (p == 4) {
        float e = (c < 10) ? (-dv * logf(dv + 1e-8f)) : 0.f;
        e += __shfl_xor(e, 1, 16);
        e += __shfl_xor(e, 2, 16);
        e += __shfl_xor(e, 4, 16);
        e += __shfl_xor(e, 8, 16);
        if (c == 0) {
            float prev = (it == 0) ? 0.f : ytacc[row];
            ytacc[row] = prev + e;
        }
    }
}

// ---------------------------------------------------------------------------
// MLP layers 1+2 for one level
// ---------------------------------------------------------------------------
__global__ __launch_bounds__(256) void mlp12_kernel(const float* __restrict__ Xs,
                                                    const float* __restrict__ w1,
                                                    const float* __restrict__ b1,
                                                    const float* __restrict__ w2,
                                                    const float* __restrict__ b2,
                                                    float* __restrict__ H2, int lvl)
{
    __shared__ float xsh[8][300];
    __shared__ float h1[8][152];
    const int t = threadIdx.x;
    const size_t r0 = (size_t)blockIdx.x * 8;
    for (int i = t; i < 2400; i += 256) xsh[i / 300][i % 300] = Xs[r0 * 300 + i];
    __syncthreads();
    if (t < 150) {
        float acc[8];
#pragma unroll
        for (int r = 0; r < 8; ++r) acc[r] = b1[t];
        for (int k = 0; k < 300; ++k) {
            float wv = w1[(size_t)k * 150 + t];
#pragma unroll
            for (int r = 0; r < 8; ++r) acc[r] = fmaf(xsh[r][k], wv, acc[r]);
        }
#pragma unroll
        for (int r = 0; r < 8; ++r) h1[r][t] = fmaxf(acc[r], 0.f);
    }
    __syncthreads();
    if (t < 75) {
        float acc[8];
#pragma unroll
        for (int r = 0; r < 8; ++r) acc[r] = b2[t];
        for (int k = 0; k < 150; ++k) {
            float wv = w2[(size_t)k * 75 + t];
#pragma unroll
            for (int r = 0; r < 8; ++r) acc[r] = fmaf(h1[r][k], wv, acc[r]);
        }
#pragma unroll
        for (int r = 0; r < 8; ++r) H2[(r0 + r) * 300 + lvl * 75 + t] = fmaxf(acc[r], 0.f);
    }
}

// ---------------------------------------------------------------------------
// Final: y_pred = H2 @ w3 + b3; y_true = ytacc/30; labelled_mask
// ---------------------------------------------------------------------------
__global__ __launch_bounds__(256) void final_kernel(const float* __restrict__ H2,
                                                    const float* __restrict__ w3,
                                                    const float* __restrict__ b3,
                                                    const float* __restrict__ ytacc,
                                                    float* __restrict__ out)
{
    __shared__ float w[300];
    const int t = threadIdx.x;
    const int b = blockIdx.x * 256 + t;
    for (int i = t; i < 300; i += 256) w[i] = w3[i];
    __syncthreads();
    float acc = b3[0];
    const float4* row = (const float4*)(H2 + (size_t)b * 300);
    for (int k4 = 0; k4 < 75; ++k4) {
        float4 v = row[k4];
        acc += v.x * w[k4 * 4] + v.y * w[k4 * 4 + 1] + v.z * w[k4 * 4 + 2] + v.w * w[k4 * 4 + 3];
    }
    out[b] = acc;
    out[4096 + b] = ytacc[b] * (1.0f / 30.0f);
    out[2 * 4096 + b] = (b < 2048) ? 1.0f : 0.0f;
}

// ---------------------------------------------------------------------------
extern "C" void kernel_launch(void* const* d_in, const int* in_sizes, int n_in,
                              void* d_out, int out_size, void* d_ws, size_t ws_size,
                              hipStream_t stream)
{
    (void)in_sizes; (void)n_in; (void)out_size;

    const float* feats[4] = {(const float*)d_in[0], (const float*)d_in[1],
                             (const float*)d_in[2], (const float*)d_in[3]};
    const float* embedds = (const float*)d_in[4];
    const int* labels = (const int*)d_in[6];
    const float* lsw[4] = {(const float*)d_in[7], (const float*)d_in[9],
                           (const float*)d_in[11], (const float*)d_in[13]};
    const float* lsb[4] = {(const float*)d_in[8], (const float*)d_in[10],
                           (const float*)d_in[12], (const float*)d_in[14]};
    const float* w1 = (const float*)d_in[15];
    const float* b1 = (const float*)d_in[16];
    const float* w2 = (const float*)d_in[17];
    const float* b2 = (const float*)d_in[18];
    const float* w3 = (const float*)d_in[19];
    const float* b3 = (const float*)d_in[20];

    // fused path: 5 Abar matrices resident (5*32MB); else 1 reused
    const bool fused = ws_size >= 211603968ULL;
    const size_t AB_BYTES = fused ? 167772160ULL : 33554432ULL;

    char* ws = (char*)d_ws;
    __half* AbarB   = (__half*)(ws);
    char* base      = ws + AB_BYTES;
    float* pooled   = (float*)(base);                 //  8388608
    __half* N16     = (__half*)(base + 8388608);      //  4194304
    __half* Xt16    = (__half*)(base + 12582912);     //  2 x 655360
    float* X32      = (float*)(base + 13893632);      //  2 x 819200
    float* Xs       = (float*)(base + 15532032);      //  19660800 (4 problems)
    float* H2       = (float*)(base + 35192832);      //  4915200
    float* ytacc    = (float*)(base + 40108032);      //  16384
    float* partials = (float*)(base + 40124416);      //  4096
    float* scal     = (float*)(base + 40128512);      //  256

    __half* Xt16b[2] = {Xt16, Xt16 + 327680};
    float* X32b[2]   = {X32, X32 + 204800};
    float* out = (float*)d_out;

    const int Cs[4] = {64, 128, 256, 512};
    const int S2s[4] = {64, 64, 16, 16};

    auto run_iters = [&](const __half* Ab, int pbase, int nprob) {
        init_kernel<<<1280, 256, 0, stream>>>(labels, Xt16b[0], Xt16b[1], X32b[0]);
        for (int it = 0; it < 30; ++it) {
            const int i = it & 1, o = i ^ 1;
            gtg_mfma_kernel<<<nprob * 256, 256, 0, stream>>>(
                Ab, Xt16b[i], Xt16b[o], X32b[i], X32b[o], Xs, ytacc, it, pbase);
        }
    };

    for (int lvl = 0; lvl < 4; ++lvl) {
        const int c = Cs[lvl];
        const int total = 4096 * c;
        if (S2s[lvl] == 64)
            pool_kernel<64><<<total / 256, 256, 0, stream>>>(feats[lvl], pooled, total);
        else
            pool_kernel<16><<<total / 256, 256, 0, stream>>>(feats[lvl], pooled, total);
        ls_norm_kernel<<<4096, 128, 0, stream>>>(pooled, lsw[lvl], lsb[lvl], N16, c);
        __half* Ab = AbarB + (fused ? (size_t)lvl * 16777216 : 0);
        a_gemm_mfma<<<1024, 256, 0, stream>>>(N16, Ab, partials, 128);
        mean_kernel<<<1, 256, 0, stream>>>(partials, scal);
        abar_kernel<<<8192, 256, 0, stream>>>(Ab, Ab, scal);
        if (!fused) {
            run_iters(Ab, lvl, 1);
            mlp12_kernel<<<512, 256, 0, stream>>>(Xs + (size_t)lvl * 1228800,
                                                  w1, b1, w2, b2, H2, lvl);
        }
    }

    // embeddings branch
    norm512_kernel<<<4096, 256, 0, stream>>>(embedds, N16);
    {
        __half* Ab = AbarB + (fused ? (size_t)4 * 16777216 : 0);
        a_gemm_mfma<<<1024, 256, 0, stream>>>(N16, Ab, partials, 512);
        mean_kernel<<<1, 256, 0, stream>>>(partials, scal);
        abar_kernel<<<8192, 256, 0, stream>>>(Ab, Ab, scal);
        if (!fused) run_iters(Ab, 4, 1);
    }

    if (fused) {
        run_iters(AbarB, 0, 5);
        for (int lvl = 0; lvl < 4; ++lvl)
            mlp12_kernel<<<512, 256, 0, stream>>>(Xs + (size_t)lvl * 1228800,
                                                  w1, b1, w2, b2, H2, lvl);
    }

    final_kernel<<<16, 256, 0, stream>>>(H2, w3, b3, ytacc, out);
}